// Round 10
// baseline (182.840 us; speedup 1.0000x reference)
//
#include <hip/hip_runtime.h>

// VQ: N=262144 rows, DIM=64, K=1024 codes.
// Stage 1: 16x16x32 f16 MFMA, 3-product split with lo-terms pre-scaled 2^12:
//   score = (ah.bh + e2-init) + (al.bh + ah.bl)*2^-12, al/bl = (q - fp16(q))*4096.
//   Exact float top-2 (m1v/m2v) + winner tile index (m1c) per lane; margin is
//   exact to ~2e-4 accumulation error. 32 rows/wave, two 16-row A-sets share
//   each B read; B tiles from L2, sequential order, compiler unroll-2.
// Stage 2: exact fp32 re-solve of rows flagged with margin < FLAG_EPS (~0.03%).
// np.argmin first-min tie-break: strict < over ascending ct keeps earliest;
//   cross-lane reduce tie-breaks on full code; near-ties re-solved exactly.

#define VQ_N 262144
#define VQ_DIM 64
#define VQ_K 1024
#define NT 64                   // 64 code-tiles of 16 codes
#define TCH 256                 // 16B chunks per tile (128 hi + 128 lo) = 4096 B
#define FLAG_EPS 1.5e-3f
#define LO_SCALE 4096.0f
#define LO_INV   2.44140625e-4f  // 2^-12

typedef _Float16 half8 __attribute__((ext_vector_type(8)));
typedef float f32x4 __attribute__((ext_vector_type(4)));

// ws layout (bytes)
#define WS_BFRAG 0                   // 64 tiles * 4096 B = 262144
#define WS_E2    (256*1024)          // float[1024] raw ||e||^2
#define WS_FLAGS (260*1024)          // u32[8192], word w covers rows 32w..32w+31
#define WS_NEEDED (292*1024)

// ---------------- prep: B fragments (hi / scaled-lo), e2, zero flags ----------------
// chunk t = ct*256 + arr*128 + kc*64 + l   (arr: 0=hi 1=lo; kc: K-chunk)
// content: 8 f16 of embed[ct*16 + (l&15)][kc*32 + (l>>4)*8 + j]
__global__ void vq_prep(const float* __restrict__ embed, unsigned char* ws) {
    int t = blockIdx.x * 256 + threadIdx.x;     // 0 .. 17407
    unsigned* flags = (unsigned*)(ws + WS_FLAGS);
    if (t < 8192) flags[t] = 0u;
    if (t < NT * TCH) {
        int ct = t >> 8;
        int c = t & 255;
        int arr = c >> 7;
        int kc = (c >> 6) & 1;
        int l = c & 63;
        int code = ct * 16 + (l & 15);
        int kbase = kc * 32 + ((l >> 4) << 3);
        const float* ep = embed + (size_t)code * VQ_DIM + kbase;
        half8 pack;
#pragma unroll
        for (int j = 0; j < 8; ++j) {
            float v = ep[j];
            _Float16 h = (_Float16)v;
            if (arr) {
                pack[j] = (_Float16)((v - (float)h) * LO_SCALE);
            } else {
                pack[j] = h;
            }
        }
        ((half8*)(ws + WS_BFRAG))[t] = pack;
    } else if (t < NT * TCH + VQ_K) {
        int code = t - NT * TCH;
        const float* ep = embed + (size_t)code * VQ_DIM;
        float a0 = 0, a1 = 0, a2 = 0, a3 = 0;
#pragma unroll
        for (int j = 0; j < VQ_DIM; j += 4) {
            a0 = fmaf(ep[j], ep[j], a0);
            a1 = fmaf(ep[j + 1], ep[j + 1], a1);
            a2 = fmaf(ep[j + 2], ep[j + 2], a2);
            a3 = fmaf(ep[j + 3], ep[j + 3], a3);
        }
        ((float*)(ws + WS_E2))[code] = (a0 + a1) + (a2 + a3);
    }
}

// ---------------- stage 1: scan + gather + flags ----------------
__global__ __launch_bounds__(256, 4)
void vq_stage1(const float* __restrict__ x, const float* __restrict__ embed,
               unsigned char* ws, float* __restrict__ out) {
    __shared__ int idx_s[4][32];        // winner code per wave-row

    const int tid = threadIdx.x;
    const int lane = tid & 63;
    const int wave = tid >> 6;
    const int gwave = blockIdx.x * 4 + wave;   // owns 32 rows
    const int R0 = gwave * 32;
    const int g = lane >> 4;            // 0..3
    const int res = lane & 15;          // code residue within tile
    const int khalf = g << 3;           // A-frag k-offset within 32-chunk

    const half8* bsrc = (const half8*)(ws + WS_BFRAG);
    const float* e2g = (const float*)(ws + WS_E2);
    unsigned* flags = (unsigned*)(ws + WS_FLAGS);

    // ---- A fragments: -2x, fp16 hi + scaled lo, two 16-row sets ----
    half8 ah00, ah01, al00, al01, ah10, ah11, al10, al11;
#define MAKE_A(ROW, KC, AH, AL)                                             \
    {                                                                       \
        const float4* p4 = (const float4*)(x + (size_t)(ROW) * VQ_DIM +     \
                                           (KC) * 32 + khalf);              \
        float4 v0 = p4[0], v1 = p4[1];                                      \
        float q0 = -2.0f * v0.x, q1 = -2.0f * v0.y, q2 = -2.0f * v0.z,      \
              q3 = -2.0f * v0.w, q4 = -2.0f * v1.x, q5 = -2.0f * v1.y,      \
              q6 = -2.0f * v1.z, q7 = -2.0f * v1.w;                         \
        _Float16 h0 = (_Float16)q0, h1 = (_Float16)q1, h2 = (_Float16)q2,   \
                 h3 = (_Float16)q3, h4 = (_Float16)q4, h5 = (_Float16)q5,   \
                 h6 = (_Float16)q6, h7 = (_Float16)q7;                      \
        AH[0] = h0; AH[1] = h1; AH[2] = h2; AH[3] = h3;                     \
        AH[4] = h4; AH[5] = h5; AH[6] = h6; AH[7] = h7;                     \
        AL[0] = (_Float16)((q0 - (float)h0) * LO_SCALE);                    \
        AL[1] = (_Float16)((q1 - (float)h1) * LO_SCALE);                    \
        AL[2] = (_Float16)((q2 - (float)h2) * LO_SCALE);                    \
        AL[3] = (_Float16)((q3 - (float)h3) * LO_SCALE);                    \
        AL[4] = (_Float16)((q4 - (float)h4) * LO_SCALE);                    \
        AL[5] = (_Float16)((q5 - (float)h5) * LO_SCALE);                    \
        AL[6] = (_Float16)((q6 - (float)h6) * LO_SCALE);                    \
        AL[7] = (_Float16)((q7 - (float)h7) * LO_SCALE);                    \
    }
    const int row0 = R0 + res;
    const int row1 = row0 + 16;
    MAKE_A(row0, 0, ah00, al00)
    MAKE_A(row0, 1, ah01, al01)
    MAKE_A(row1, 0, ah10, al10)
    MAKE_A(row1, 1, ah11, al11)
#undef MAKE_A

    const f32x4 zero4 = {0.0f, 0.0f, 0.0f, 0.0f};
    float m1v0[4], m2v0[4], m1v1[4], m2v1[4];
    unsigned m1c0[4], m1c1[4];
#pragma unroll
    for (int r = 0; r < 4; ++r) {
        m1v0[r] = __builtin_inff(); m2v0[r] = __builtin_inff(); m1c0[r] = 0u;
        m1v1[r] = __builtin_inff(); m2v1[r] = __builtin_inff(); m1c1[r] = 0u;
    }

    // ---- main scan (sequential tiles, compiler prefetch) ----
#pragma unroll 2
    for (int ct = 0; ct < NT; ++ct) {
        const half8* bt = bsrc + (size_t)ct * TCH;
        half8 bh0 = bt[lane];
        half8 bh1 = bt[64 + lane];
        half8 bl0 = bt[128 + lane];
        half8 bl1 = bt[192 + lane];
        float e2c = e2g[ct * 16 + res];
        unsigned ctu = (unsigned)ct;

        // set 0: independent chains accm (hi.hi + e2) and accc (scaled lo terms)
        f32x4 am0 = {e2c, e2c, e2c, e2c};
        f32x4 ac0;
        ac0 = __builtin_amdgcn_mfma_f32_16x16x32_f16(al00, bh0, zero4, 0, 0, 0);
        am0 = __builtin_amdgcn_mfma_f32_16x16x32_f16(ah00, bh0, am0, 0, 0, 0);
        ac0 = __builtin_amdgcn_mfma_f32_16x16x32_f16(al01, bh1, ac0, 0, 0, 0);
        am0 = __builtin_amdgcn_mfma_f32_16x16x32_f16(ah01, bh1, am0, 0, 0, 0);
        ac0 = __builtin_amdgcn_mfma_f32_16x16x32_f16(ah00, bl0, ac0, 0, 0, 0);
        ac0 = __builtin_amdgcn_mfma_f32_16x16x32_f16(ah01, bl1, ac0, 0, 0, 0);

        // set 1
        f32x4 am1 = {e2c, e2c, e2c, e2c};
        f32x4 ac1;
        ac1 = __builtin_amdgcn_mfma_f32_16x16x32_f16(al10, bh0, zero4, 0, 0, 0);
        am1 = __builtin_amdgcn_mfma_f32_16x16x32_f16(ah10, bh0, am1, 0, 0, 0);
        ac1 = __builtin_amdgcn_mfma_f32_16x16x32_f16(al11, bh1, ac1, 0, 0, 0);
        am1 = __builtin_amdgcn_mfma_f32_16x16x32_f16(ah11, bh1, am1, 0, 0, 0);
        ac1 = __builtin_amdgcn_mfma_f32_16x16x32_f16(ah10, bl0, ac1, 0, 0, 0);
        ac1 = __builtin_amdgcn_mfma_f32_16x16x32_f16(ah11, bl1, ac1, 0, 0, 0);

#pragma unroll
        for (int r = 0; r < 4; ++r) {
            float s = fmaf(ac0[r], LO_INV, am0[r]);
            bool c = s < m1v0[r];
            float mx = fmaxf(m1v0[r], s);
            m2v0[r] = fminf(m2v0[r], mx);
            m1v0[r] = fminf(m1v0[r], s);
            m1c0[r] = c ? ctu : m1c0[r];
        }
#pragma unroll
        for (int r = 0; r < 4; ++r) {
            float s = fmaf(ac1[r], LO_INV, am1[r]);
            bool c = s < m1v1[r];
            float mx = fmaxf(m1v1[r], s);
            m2v1[r] = fminf(m2v1[r], mx);
            m1v1[r] = fminf(m1v1[r], s);
            m1c1[r] = c ? ctu : m1c1[r];
        }
    }

    // ---- full code per lane, then reduce over the 16 residues ----
    int code0[4], code1[4];
#pragma unroll
    for (int r = 0; r < 4; ++r) {
        code0[r] = (int)(m1c0[r] * 16u) + res;
        code1[r] = (int)(m1c1[r] * 16u) + res;
    }
#define RED_STEP(MV, M2, CODE, m)                                                     \
    {                                                                                 \
        _Pragma("unroll")                                                             \
        for (int r = 0; r < 4; ++r) {                                                 \
            float ov = __shfl_xor(MV[r], m);                                          \
            float om2 = __shfl_xor(M2[r], m);                                         \
            int oc = __shfl_xor(CODE[r], m);                                          \
            float mx = fmaxf(MV[r], ov);                                              \
            float c2 = fminf(om2, mx);                                                \
            M2[r] = fminf(M2[r], c2);                                                 \
            bool take = (ov < MV[r]) || (ov == MV[r] && oc < CODE[r]);                \
            if (take) { MV[r] = ov; CODE[r] = oc; }                                   \
        }                                                                             \
    }
#pragma unroll
    for (int m = 1; m <= 8; m <<= 1) {
        RED_STEP(m1v0, m2v0, code0, m)
        RED_STEP(m1v1, m2v1, code1, m)
    }
#undef RED_STEP

    // ---- lanes 0/16/32/48 publish idx + margin flags for rows 4g+0..3 ----
    unsigned fmask = 0;
    if (res == 0) {
#pragma unroll
        for (int r = 0; r < 4; ++r) {
            int rl0 = 4 * g + r;
            idx_s[wave][rl0] = code0[r];
            if (m2v0[r] - m1v0[r] < FLAG_EPS) fmask |= 1u << rl0;
            int rl1 = 16 + 4 * g + r;
            idx_s[wave][rl1] = code1[r];
            if (m2v1[r] - m1v1[r] < FLAG_EPS) fmask |= 1u << rl1;
        }
    }
    fmask |= (unsigned)__shfl_xor((int)fmask, 16);
    fmask |= (unsigned)__shfl_xor((int)fmask, 32);
    if (lane == 0) flags[gwave] = fmask;
    __syncthreads();

    // ---- gather embed[idx] -> out (2 threads per row) ----
    const int orow = tid >> 1;              // 0..127
    const int ohalf = tid & 1;
    int code = idx_s[orow >> 5][orow & 31];
    const float4* ep = (const float4*)(embed + (size_t)code * VQ_DIM) + ohalf * 8;
    float4* op = (float4*)(out + (size_t)(blockIdx.x * 128 + orow) * VQ_DIM) + ohalf * 8;
#pragma unroll
    for (int j = 0; j < 8; ++j) op[j] = ep[j];
}

// ---------------- stage 2: exact fp32 re-solve of flagged rows (~0.03%) ----------------
__global__ __launch_bounds__(256, 4)
void vq_stage2(const float* __restrict__ x, const float* __restrict__ embed,
               unsigned char* ws, float* __restrict__ out) {
    const unsigned* flags = (const unsigned*)(ws + WS_FLAGS);
    const float* e2 = (const float*)(ws + WS_E2);
    int lane = threadIdx.x & 63;
    int wave = threadIdx.x >> 6;
    int w = blockIdx.x * 4 + wave;
    int rowbase = w * 64;
    unsigned fw = flags[(rowbase >> 5) + (lane >> 5)];
    int bit = (fw >> (lane & 31)) & 1;
    unsigned long long ball = __ballot(bit);
    while (ball) {
        int b = __ffsll(ball) - 1;
        ball &= ball - 1;
        int row = rowbase + b;
        const float* xr = x + (size_t)row * VQ_DIM;
        float best = __builtin_inff();
        int bi = VQ_K;
        for (int t = 0; t < VQ_K / 64; ++t) {
            int c = t * 64 + lane;
            const float* ep = embed + (size_t)c * VQ_DIM;
            float a0 = 0, a1 = 0, a2 = 0, a3 = 0;
#pragma unroll
            for (int j = 0; j < VQ_DIM; j += 4) {
                a0 = fmaf(xr[j], ep[j], a0);
                a1 = fmaf(xr[j + 1], ep[j + 1], a1);
                a2 = fmaf(xr[j + 2], ep[j + 2], a2);
                a3 = fmaf(xr[j + 3], ep[j + 3], a3);
            }
            float dot = (a0 + a1) + (a2 + a3);
            float s = fmaf(-2.0f, dot, e2[c]);
            if (s < best || (s == best && c < bi)) { best = s; bi = c; }
        }
#pragma unroll
        for (int m = 1; m <= 32; m <<= 1) {
            float ob = __shfl_xor(best, m);
            int oi = __shfl_xor(bi, m);
            if (ob < best || (ob == best && oi < bi)) { best = ob; bi = oi; }
        }
        out[(size_t)row * VQ_DIM + lane] = embed[(size_t)bi * VQ_DIM + lane];
    }
}

// ---------------- fallback (round-1 fp32, only if ws too small) ----------------
__global__ __launch_bounds__(256, 4)
void vq_fallback(const float* __restrict__ x, const float* __restrict__ embed,
                 float* __restrict__ out) {
    __shared__ float e2s[VQ_K];
    const int tid = threadIdx.x;
    for (int c = tid; c < VQ_K; c += 256) {
        const float4* ep = (const float4*)(embed + c * VQ_DIM);
        float s = 0.0f;
#pragma unroll
        for (int j = 0; j < VQ_DIM / 4; ++j) {
            float4 v = ep[j];
            s = fmaf(v.x, v.x, s); s = fmaf(v.y, v.y, s);
            s = fmaf(v.z, v.z, s); s = fmaf(v.w, v.w, s);
        }
        e2s[c] = s;
    }
    __syncthreads();
    const int row = blockIdx.x * 256 + tid;
    float xr[VQ_DIM];
    const float4* xp = (const float4*)(x + (size_t)row * VQ_DIM);
#pragma unroll
    for (int j = 0; j < VQ_DIM / 4; ++j) {
        float4 v = xp[j];
        xr[4 * j] = v.x; xr[4 * j + 1] = v.y; xr[4 * j + 2] = v.z; xr[4 * j + 3] = v.w;
    }
    float best = __builtin_inff();
    int bidx = 0;
    for (int c = 0; c < VQ_K; ++c) {
        const float4* ep = (const float4*)(embed + c * VQ_DIM);
        float a0 = 0, a1 = 0, a2 = 0, a3 = 0;
#pragma unroll
        for (int j = 0; j < VQ_DIM / 4; ++j) {
            float4 v = ep[j];
            a0 = fmaf(xr[4 * j], v.x, a0);
            a1 = fmaf(xr[4 * j + 1], v.y, a1);
            a2 = fmaf(xr[4 * j + 2], v.z, a2);
            a3 = fmaf(xr[4 * j + 3], v.w, a3);
        }
        float score = fmaf(-2.0f, (a0 + a1) + (a2 + a3), e2s[c]);
        if (score < best) { best = score; bidx = c; }
    }
    const float4* bp = (const float4*)(embed + (size_t)bidx * VQ_DIM);
    float4* op = (float4*)(out + (size_t)row * VQ_DIM);
#pragma unroll
    for (int j = 0; j < VQ_DIM / 4; ++j) op[j] = bp[j];
}

extern "C" void kernel_launch(void* const* d_in, const int* in_sizes, int n_in,
                              void* d_out, int out_size, void* d_ws, size_t ws_size,
                              hipStream_t stream) {
    const float* x = (const float*)d_in[0];
    const float* embed = (const float*)d_in[1];
    float* out = (float*)d_out;
    if (ws_size < WS_NEEDED) {
        hipLaunchKernelGGL(vq_fallback, dim3(VQ_N / 256), dim3(256), 0, stream, x, embed, out);
        return;
    }
    unsigned char* ws = (unsigned char*)d_ws;
    hipLaunchKernelGGL(vq_prep, dim3(68), dim3(256), 0, stream, embed, ws);
    hipLaunchKernelGGL(vq_stage1, dim3(VQ_N / 128), dim3(256), 0, stream, x, embed, ws, out);
    hipLaunchKernelGGL(vq_stage2, dim3(VQ_N / 256), dim3(256), 0, stream, x, embed, ws, out);
}

// Round 11
// 176.498 us; speedup vs baseline: 1.0359x; 1.0359x over previous
//
#include <hip/hip_runtime.h>

// VQ: N=262144 rows, DIM=64, K=1024 codes.
// Single-wave blocks (64 thr, 8192 blocks), zero LDS / zero barriers.
// Scan (R6-proven): 16x16x32 bf16 MFMA, 3-product hi/lo split, acc init
//   = ||e||^2 + 256 (positive scores -> raw bits order-preserving),
//   key = (bits & ~63) | ct, 4-op top2. 32 rows/wave, two 16-row A-sets
//   share each B read; B tiles from L2, sequential order, compiler unroll-2.
// Publish + gather + margin flags fully in-wave via shfl; rows with top2
//   margin < FLAG_EPS re-solved exactly in-wave (fp32, no reg array).
// np.argmin first-min tie-break preserved (ct in key LSBs + residue
//   tie-break; near-ties re-solved exactly with index-ordered selection).

#define VQ_N 262144
#define VQ_DIM 64
#define VQ_K 1024
#define NT 64                   // 64 code-tiles of 16 codes
#define TCH 256                 // 16B chunks per tile (128 hi + 128 lo) = 4096 B
#define FLAG_EPS 1.2e-2f

typedef short short8 __attribute__((ext_vector_type(8)));
typedef float f32x4 __attribute__((ext_vector_type(4)));

// ws layout (bytes)
#define WS_BFRAG 0                   // 64 tiles * 4096 B = 262144
#define WS_E2    (256*1024)          // float[1024] raw ||e||^2 (resolve)
#define WS_E2P   (260*1024)          // float[1024] ||e||^2 + 256 (scan init)
#define WS_NEEDED (264*1024)

static __device__ __forceinline__ unsigned short f2bf_rtne(float f) {
    unsigned u = __float_as_uint(f);
    unsigned r = u + 0x7FFFu + ((u >> 16) & 1u);
    return (unsigned short)(r >> 16);
}
static __device__ __forceinline__ float bf2f(unsigned short h) {
    return __uint_as_float(((unsigned)h) << 16);
}

// ---------------- prep: B fragments (hi/lo), e2 / e2+256 ----------------
// chunk t = ct*256 + arr*128 + kc*64 + l   (arr: 0=hi 1=lo; kc: K-chunk)
// content: 8 bf16 of embed[ct*16 + (l&15)][kc*32 + (l>>4)*8 + j]
__global__ void vq_prep(const float* __restrict__ embed, unsigned char* ws) {
    int t = blockIdx.x * 256 + threadIdx.x;     // 0 .. 17407
    if (t < NT * TCH) {
        int ct = t >> 8;
        int c = t & 255;
        int arr = c >> 7;
        int kc = (c >> 6) & 1;
        int l = c & 63;
        int code = ct * 16 + (l & 15);
        int kbase = kc * 32 + ((l >> 4) << 3);
        const float* ep = embed + (size_t)code * VQ_DIM + kbase;
        short8 pack;
#pragma unroll
        for (int j = 0; j < 8; ++j) {
            float v = ep[j];
            unsigned short h = f2bf_rtne(v);
            pack[j] = arr ? (short)f2bf_rtne(v - bf2f(h)) : (short)h;
        }
        ((short8*)(ws + WS_BFRAG))[t] = pack;
    } else if (t < NT * TCH + VQ_K) {
        int code = t - NT * TCH;
        const float* ep = embed + (size_t)code * VQ_DIM;
        float a0 = 0, a1 = 0, a2 = 0, a3 = 0;
#pragma unroll
        for (int j = 0; j < VQ_DIM; j += 4) {
            a0 = fmaf(ep[j], ep[j], a0);
            a1 = fmaf(ep[j + 1], ep[j + 1], a1);
            a2 = fmaf(ep[j + 2], ep[j + 2], a2);
            a3 = fmaf(ep[j + 3], ep[j + 3], a3);
        }
        float e2 = (a0 + a1) + (a2 + a3);
        ((float*)(ws + WS_E2))[code] = e2;
        ((float*)(ws + WS_E2P))[code] = e2 + 256.0f;
    }
}

// ---------------- stage 1: scan + in-wave publish/gather/resolve ----------------
__global__ __launch_bounds__(64, 4)
void vq_stage1(const float* __restrict__ x, const float* __restrict__ embed,
               unsigned char* ws, float* __restrict__ out) {
    const int lane = threadIdx.x;       // 0..63
    const int gwave = blockIdx.x;       // 0..8191, owns 32 rows
    const int R0 = gwave * 32;
    const int g = lane >> 4;            // 0..3
    const int res = lane & 15;
    const int khalf = g << 3;           // A-frag k-offset within 32-chunk

    const short8* bsrc = (const short8*)(ws + WS_BFRAG);
    const float* e2g = (const float*)(ws + WS_E2);
    const float* e2p = (const float*)(ws + WS_E2P);

    // ---- A fragments: -2x hi/lo, two 16-row sets, named scalars ----
    short8 ah00, ah01, al00, al01, ah10, ah11, al10, al11;
#define MAKE_A(ROW, KC, AH, AL)                                             \
    {                                                                       \
        const float4* p4 = (const float4*)(x + (size_t)(ROW) * VQ_DIM +     \
                                           (KC) * 32 + khalf);              \
        float4 v0 = p4[0], v1 = p4[1];                                      \
        float q0 = -2.0f * v0.x, q1 = -2.0f * v0.y, q2 = -2.0f * v0.z,      \
              q3 = -2.0f * v0.w, q4 = -2.0f * v1.x, q5 = -2.0f * v1.y,      \
              q6 = -2.0f * v1.z, q7 = -2.0f * v1.w;                         \
        unsigned short h0 = f2bf_rtne(q0), h1 = f2bf_rtne(q1),              \
                       h2 = f2bf_rtne(q2), h3 = f2bf_rtne(q3),              \
                       h4 = f2bf_rtne(q4), h5 = f2bf_rtne(q5),              \
                       h6 = f2bf_rtne(q6), h7 = f2bf_rtne(q7);              \
        AH[0] = (short)h0; AH[1] = (short)h1; AH[2] = (short)h2;            \
        AH[3] = (short)h3; AH[4] = (short)h4; AH[5] = (short)h5;            \
        AH[6] = (short)h6; AH[7] = (short)h7;                               \
        AL[0] = (short)f2bf_rtne(q0 - bf2f(h0));                            \
        AL[1] = (short)f2bf_rtne(q1 - bf2f(h1));                            \
        AL[2] = (short)f2bf_rtne(q2 - bf2f(h2));                            \
        AL[3] = (short)f2bf_rtne(q3 - bf2f(h3));                            \
        AL[4] = (short)f2bf_rtne(q4 - bf2f(h4));                            \
        AL[5] = (short)f2bf_rtne(q5 - bf2f(h5));                            \
        AL[6] = (short)f2bf_rtne(q6 - bf2f(h6));                            \
        AL[7] = (short)f2bf_rtne(q7 - bf2f(h7));                            \
    }
    const int row0 = R0 + res;
    const int row1 = row0 + 16;
    MAKE_A(row0, 0, ah00, al00)
    MAKE_A(row0, 1, ah01, al01)
    MAKE_A(row1, 0, ah10, al10)
    MAKE_A(row1, 1, ah11, al11)
#undef MAKE_A

    unsigned m1k0[4], m2k0[4], m1k1[4], m2k1[4];
#pragma unroll
    for (int r = 0; r < 4; ++r) {
        m1k0[r] = 0xFFFFFFFFu; m2k0[r] = 0xFFFFFFFFu;
        m1k1[r] = 0xFFFFFFFFu; m2k1[r] = 0xFFFFFFFFu;
    }

    // ---- main scan (R6 structure: sequential tiles, compiler prefetch) ----
#pragma unroll 2
    for (int ct = 0; ct < NT; ++ct) {
        const short8* bt = bsrc + (size_t)ct * TCH;
        short8 bh0 = bt[lane];
        short8 bh1 = bt[64 + lane];
        short8 bl0 = bt[128 + lane];
        short8 bl1 = bt[192 + lane];
        float e2c = e2p[ct * 16 + res];
        unsigned ctu = (unsigned)ct;

        f32x4 acc0 = {e2c, e2c, e2c, e2c};
        acc0 = __builtin_amdgcn_mfma_f32_16x16x32_bf16(al00, bh0, acc0, 0, 0, 0);
        acc0 = __builtin_amdgcn_mfma_f32_16x16x32_bf16(al01, bh1, acc0, 0, 0, 0);
        acc0 = __builtin_amdgcn_mfma_f32_16x16x32_bf16(ah00, bl0, acc0, 0, 0, 0);
        acc0 = __builtin_amdgcn_mfma_f32_16x16x32_bf16(ah01, bl1, acc0, 0, 0, 0);
        acc0 = __builtin_amdgcn_mfma_f32_16x16x32_bf16(ah00, bh0, acc0, 0, 0, 0);
        acc0 = __builtin_amdgcn_mfma_f32_16x16x32_bf16(ah01, bh1, acc0, 0, 0, 0);

        f32x4 acc1 = {e2c, e2c, e2c, e2c};
        acc1 = __builtin_amdgcn_mfma_f32_16x16x32_bf16(al10, bh0, acc1, 0, 0, 0);
        acc1 = __builtin_amdgcn_mfma_f32_16x16x32_bf16(al11, bh1, acc1, 0, 0, 0);
        acc1 = __builtin_amdgcn_mfma_f32_16x16x32_bf16(ah10, bl0, acc1, 0, 0, 0);
        acc1 = __builtin_amdgcn_mfma_f32_16x16x32_bf16(ah11, bl1, acc1, 0, 0, 0);
        acc1 = __builtin_amdgcn_mfma_f32_16x16x32_bf16(ah10, bh0, acc1, 0, 0, 0);
        acc1 = __builtin_amdgcn_mfma_f32_16x16x32_bf16(ah11, bh1, acc1, 0, 0, 0);

#pragma unroll
        for (int r = 0; r < 4; ++r) {
            unsigned key = (__float_as_uint(acc0[r]) & 0xFFFFFFC0u) | ctu;
            unsigned t1 = m1k0[r] > key ? m1k0[r] : key;
            m2k0[r] = m2k0[r] < t1 ? m2k0[r] : t1;
            m1k0[r] = m1k0[r] < key ? m1k0[r] : key;
        }
#pragma unroll
        for (int r = 0; r < 4; ++r) {
            unsigned key = (__float_as_uint(acc1[r]) & 0xFFFFFFC0u) | ctu;
            unsigned t1 = m1k1[r] > key ? m1k1[r] : key;
            m2k1[r] = m2k1[r] < t1 ? m2k1[r] : t1;
            m1k1[r] = m1k1[r] < key ? m1k1[r] : key;
        }
    }

    // ---- reduce over the 16 codes (lanes within each 16-group) ----
    unsigned res0[4], res1[4];
#pragma unroll
    for (int r = 0; r < 4; ++r) { res0[r] = (unsigned)res; res1[r] = res0[r]; }
#define RED_STEP(M1, M2, RES, m)                                                      \
    {                                                                                 \
        _Pragma("unroll")                                                             \
        for (int r = 0; r < 4; ++r) {                                                 \
            unsigned ok = (unsigned)__shfl_xor((int)M1[r], m);                        \
            unsigned ok2 = (unsigned)__shfl_xor((int)M2[r], m);                       \
            unsigned orr = (unsigned)__shfl_xor((int)RES[r], m);                      \
            unsigned t1 = M1[r] > ok ? M1[r] : ok;                                    \
            unsigned c2 = ok2 < t1 ? ok2 : t1;                                        \
            M2[r] = M2[r] < c2 ? M2[r] : c2;                                          \
            bool take = (ok < M1[r]) || (ok == M1[r] && orr < RES[r]);                \
            if (take) { M1[r] = ok; RES[r] = orr; }                                   \
        }                                                                             \
    }
#pragma unroll
    for (int m = 1; m <= 8; m <<= 1) {
        RED_STEP(m1k0, m2k0, res0, m)
        RED_STEP(m1k1, m2k1, res1, m)
    }
#undef RED_STEP

    // ---- winner codes + margin flags (all lanes of a group agree) ----
    int code0[4], code1[4];
    unsigned fmask = 0;
#pragma unroll
    for (int r = 0; r < 4; ++r) {
        code0[r] = (int)((m1k0[r] & 63u) * 16u + res0[r]);
        code1[r] = (int)((m1k1[r] & 63u) * 16u + res1[r]);
        float s1a = __uint_as_float(m1k0[r] & 0xFFFFFFC0u);
        float s2a = __uint_as_float(m2k0[r] & 0xFFFFFFC0u);
        if (s2a - s1a < FLAG_EPS) fmask |= 1u << (4 * g + r);
        float s1b = __uint_as_float(m1k1[r] & 0xFFFFFFC0u);
        float s2b = __uint_as_float(m2k1[r] & 0xFFFFFFC0u);
        if (s2b - s1b < FLAG_EPS) fmask |= 1u << (16 + 4 * g + r);
    }
    fmask |= (unsigned)__shfl_xor((int)fmask, 16);
    fmask |= (unsigned)__shfl_xor((int)fmask, 32);
    unsigned wmask = fmask;             // full 32-row flag mask, all lanes

    // ---- in-wave gather: lane handles row q = lane>>1, half = lane&1 ----
    {
        const int q = lane >> 1;            // 0..31
        const int setq = q >> 4;            // 0/1
        const int gq = (q & 15) >> 2;       // source group
        const int rq = q & 3;
        const int src = gq << 4;
        int a0 = __shfl(code0[0], src), a1 = __shfl(code0[1], src);
        int a2 = __shfl(code0[2], src), a3 = __shfl(code0[3], src);
        int b0 = __shfl(code1[0], src), b1 = __shfl(code1[1], src);
        int b2 = __shfl(code1[2], src), b3 = __shfl(code1[3], src);
        int cs0 = (rq == 0) ? a0 : (rq == 1) ? a1 : (rq == 2) ? a2 : a3;
        int cs1 = (rq == 0) ? b0 : (rq == 1) ? b1 : (rq == 2) ? b2 : b3;
        int my = setq ? cs1 : cs0;
        const float4* ep = (const float4*)(embed + (size_t)my * VQ_DIM) + (lane & 1) * 8;
        float4* op = (float4*)(out + (size_t)(R0 + q) * VQ_DIM) + (lane & 1) * 8;
#pragma unroll
        for (int j = 0; j < 8; ++j) op[j] = ep[j];
    }

    // ---- in-wave exact fp32 re-solve of flagged rows (rare; no reg array) ----
    while (wmask) {
        int b = __ffs(wmask) - 1;
        wmask &= wmask - 1;
        int row = R0 + b;
        const float* xr = x + (size_t)row * VQ_DIM;
        float best = __builtin_inff();
        int bi = VQ_K;
        for (int t = 0; t < VQ_K / 64; ++t) {
            int c = t * 64 + lane;
            const float* ep2 = embed + (size_t)c * VQ_DIM;
            float a0 = 0, a1 = 0, a2 = 0, a3 = 0;
#pragma unroll
            for (int j = 0; j < VQ_DIM; j += 4) {
                a0 = fmaf(xr[j], ep2[j], a0);
                a1 = fmaf(xr[j + 1], ep2[j + 1], a1);
                a2 = fmaf(xr[j + 2], ep2[j + 2], a2);
                a3 = fmaf(xr[j + 3], ep2[j + 3], a3);
            }
            float dot = (a0 + a1) + (a2 + a3);
            float s = fmaf(-2.0f, dot, e2g[c]);
            if (s < best || (s == best && c < bi)) { best = s; bi = c; }
        }
#pragma unroll
        for (int m = 1; m <= 32; m <<= 1) {
            float ob = __shfl_xor(best, m);
            int oi = __shfl_xor(bi, m);
            if (ob < best || (ob == best && oi < bi)) { best = ob; bi = oi; }
        }
        out[(size_t)row * VQ_DIM + lane] = embed[(size_t)bi * VQ_DIM + lane];
    }
}

// ---------------- fallback (round-1 fp32, only if ws too small) ----------------
__global__ __launch_bounds__(256, 4)
void vq_fallback(const float* __restrict__ x, const float* __restrict__ embed,
                 float* __restrict__ out) {
    __shared__ float e2s[VQ_K];
    const int tid = threadIdx.x;
    for (int c = tid; c < VQ_K; c += 256) {
        const float4* ep = (const float4*)(embed + c * VQ_DIM);
        float s = 0.0f;
#pragma unroll
        for (int j = 0; j < VQ_DIM / 4; ++j) {
            float4 v = ep[j];
            s = fmaf(v.x, v.x, s); s = fmaf(v.y, v.y, s);
            s = fmaf(v.z, v.z, s); s = fmaf(v.w, v.w, s);
        }
        e2s[c] = s;
    }
    __syncthreads();
    const int row = blockIdx.x * 256 + tid;
    float xr[VQ_DIM];
    const float4* xp = (const float4*)(x + (size_t)row * VQ_DIM);
#pragma unroll
    for (int j = 0; j < VQ_DIM / 4; ++j) {
        float4 v = xp[j];
        xr[4 * j] = v.x; xr[4 * j + 1] = v.y; xr[4 * j + 2] = v.z; xr[4 * j + 3] = v.w;
    }
    float best = __builtin_inff();
    int bidx = 0;
    for (int c = 0; c < VQ_K; ++c) {
        const float4* ep = (const float4*)(embed + c * VQ_DIM);
        float a0 = 0, a1 = 0, a2 = 0, a3 = 0;
#pragma unroll
        for (int j = 0; j < VQ_DIM / 4; ++j) {
            float4 v = ep[j];
            a0 = fmaf(xr[4 * j], v.x, a0);
            a1 = fmaf(xr[4 * j + 1], v.y, a1);
            a2 = fmaf(xr[4 * j + 2], v.z, a2);
            a3 = fmaf(xr[4 * j + 3], v.w, a3);
        }
        float score = fmaf(-2.0f, (a0 + a1) + (a2 + a3), e2s[c]);
        if (score < best) { best = score; bidx = c; }
    }
    const float4* bp = (const float4*)(embed + (size_t)bidx * VQ_DIM);
    float4* op = (float4*)(out + (size_t)row * VQ_DIM);
#pragma unroll
    for (int j = 0; j < VQ_DIM / 4; ++j) op[j] = bp[j];
}

extern "C" void kernel_launch(void* const* d_in, const int* in_sizes, int n_in,
                              void* d_out, int out_size, void* d_ws, size_t ws_size,
                              hipStream_t stream) {
    const float* x = (const float*)d_in[0];
    const float* embed = (const float*)d_in[1];
    float* out = (float*)d_out;
    if (ws_size < WS_NEEDED) {
        hipLaunchKernelGGL(vq_fallback, dim3(VQ_N / 256), dim3(256), 0, stream, x, embed, out);
        return;
    }
    unsigned char* ws = (unsigned char*)d_ws;
    hipLaunchKernelGGL(vq_prep, dim3(68), dim3(256), 0, stream, embed, ws);
    hipLaunchKernelGGL(vq_stage1, dim3(VQ_N / 32), dim3(64), 0, stream, x, embed, ws, out);
}